// Round 7
// baseline (6527.322 us; speedup 1.0000x reference)
//
#include <hip/hip_runtime.h>
#include <hip/hip_fp16.h>

// LSTM autoencoder B=256,S=512,D=64,H=128 — MFMA rewrite.
// 16 WGs x 16 batch rows x 1024 threads (16 waves). Per step, gates^T computed
// as D[512 gates x 16 batch] = Wstack^T (A) x Hstack (B) with
// mfma_f32_16x16x32_f16; wave w owns gate-rows [32w,32w+32) = 2 tiles.
// Gate-interleaved packing (n = 4j+r) => each lane's 4 accum regs = (i,f,g,o)
// of one (batch,hidden) pair: cell update is lane-local, c-state in 4 VGPRs.
// Weights streamed from L2 each step (frag-linear packed, 1KB/wave coalesced).
// h in LDS [16][136] f16 (272B stride = 2-way bank aliasing only).
// enc: 1 barrier/step; dec: 2 (feedback fused via W' = Wih0_dec . fcW).
// fc projection: epilogue kernel, in-place in d_out.

typedef _Float16 h2 __attribute__((ext_vector_type(2)));
typedef _Float16 h8 __attribute__((ext_vector_type(8)));
typedef float f32x4 __attribute__((ext_vector_type(4)));

#define Bsz 256
#define Ssz 512
#define Hsz 128

#define MFMA16(A, B, C) __builtin_amdgcn_mfma_f32_16x16x32_f16(A, B, C, 0, 0, 0)

__device__ __forceinline__ float fdot2f(h2 a, h2 b, float c) {
#if __has_builtin(__builtin_amdgcn_fdot2)
  return __builtin_amdgcn_fdot2(a, b, c, false);
#else
  return c + (float)a[0] * (float)b[0] + (float)a[1] * (float)b[1];
#endif
}

__device__ __forceinline__ float dot8(h8 v, h8 w, float acc) {
  h2 v0 = __builtin_shufflevector(v, v, 0, 1);
  h2 v1 = __builtin_shufflevector(v, v, 2, 3);
  h2 v2 = __builtin_shufflevector(v, v, 4, 5);
  h2 v3 = __builtin_shufflevector(v, v, 6, 7);
  h2 w0 = __builtin_shufflevector(w, w, 0, 1);
  h2 w1 = __builtin_shufflevector(w, w, 2, 3);
  h2 w2 = __builtin_shufflevector(w, w, 4, 5);
  h2 w3 = __builtin_shufflevector(w, w, 6, 7);
  acc = fdot2f(v0, w0, acc);
  acc = fdot2f(v1, w1, acc);
  acc = fdot2f(v2, w2, acc);
  acc = fdot2f(v3, w3, acc);
  return acc;
}

__device__ __forceinline__ float sigm(float v) { return 1.f / (1.f + __expf(-v)); }
__device__ __forceinline__ float tanh_f(float v) { return 2.f / (1.f + __expf(-2.f * v)) - 1.f; }

__device__ __forceinline__ int permcol(int n) { return (n & 3) * 128 + (n >> 2); }

__device__ __forceinline__ h8 ldfrag(const _Float16* p, int byteoff) {
  return *(const h8*)((const char*)p + byteoff);
}

// one lane-local LSTM cell update: a = accum (i,f,g,o), bb = bias; returns h
__device__ __forceinline__ float cellup(f32x4 a, f32x4 bb, float& c) {
  float ig = sigm(a[0] + bb[0]);
  float fg = sigm(a[1] + bb[1]);
  float gg = tanh_f(a[2] + bb[2]);
  float og = sigm(a[3] + bb[3]);
  c = fg * c + ig * gg;
  return og * tanh_f(c);
}

// ================= encoder =================
__global__ void __launch_bounds__(1024)
enc_kernel(const float* __restrict__ x,
           const h8* __restrict__ W1 /*K=192: [Wih0;Whh0]*/,
           const h8* __restrict__ W2 /*K=256: [Wih1;Whh1]*/,
           const float* __restrict__ b0p, const float* __restrict__ b1p,
           float* __restrict__ st) {
  __shared__ _Float16 sH0[2][16 * 136];   // 272 B/row
  __shared__ _Float16 sH1[2][16 * 136];
  __shared__ _Float16 sX[2][16 * 72];     // 144 B/row

  const int tid = threadIdx.x;
  const int w = tid >> 6, lane = tid & 63;
  const int khi = lane >> 4, b = lane & 15;
  const int row0 = blockIdx.x << 4;
  const int aoff0 = (32 * w + b) * 4 + khi;      // A-frag h8 index, tile0
  const int aoff1 = aoff0 + 64;                  // tile1 (+16 cols * 4)
  const int j0 = 8 * w + khi, j1 = j0 + 4;
  const int pb = tid >> 6, pd = tid & 63;        // x prefetch mapping (pb==w)

  // init state buffers
  for (int i = tid; i < 16 * 136; i += 1024) { sH0[0][i] = (_Float16)0.f; sH1[0][i] = (_Float16)0.f; }
  sX[0][pb * 72 + pd] = (_Float16)x[((size_t)(row0 + pb) * Ssz + 0) * 64 + pd];

  const int nb0 = 32 * w + 4 * khi;
  const f32x4 b0a = *(const f32x4*)&b0p[nb0];
  const f32x4 b0b = *(const f32x4*)&b0p[nb0 + 16];
  const f32x4 b1a = *(const f32x4*)&b1p[nb0];
  const f32x4 b1b = *(const f32x4*)&b1p[nb0 + 16];
  float c0a = 0.f, c0b = 0.f, c1a = 0.f, c1b = 0.f;
  __syncthreads();

  for (int t = 0; t < Ssz; ++t) {
    const int cur = t & 1;
    const _Float16* H0r = sH0[cur];
    _Float16* H0w = sH0[cur ^ 1];
    const _Float16* H1r = sH1[cur];
    _Float16* H1w = sH1[cur ^ 1];
    const _Float16* Xr = sX[cur];
    _Float16* Xw = sX[cur ^ 1];

    // x(t+1) prefetch: issue early, LDS-write before the barrier
    float xv = 0.f;
    const bool pf = (t + 1 < Ssz);
    if (pf) xv = x[((size_t)(row0 + pb) * Ssz + (t + 1)) * 64 + pd];

    // ---- P1: gates0^T = [Wih0;Whh0]^T x [x_t; h0]  (K=192, 6 k-steps) ----
    f32x4 a0 = {0.f, 0.f, 0.f, 0.f}, a1 = {0.f, 0.f, 0.f, 0.f};
#pragma unroll
    for (int ks = 0; ks < 6; ++ks) {
      h8 bf;
      if (ks < 2) bf = ldfrag(Xr, b * 144 + ks * 64 + khi * 16);
      else        bf = ldfrag(H0r, b * 272 + (ks - 2) * 64 + khi * 16);
      h8 af0 = W1[ks * 2048 + aoff0];
      h8 af1 = W1[ks * 2048 + aoff1];
      a0 = MFMA16(af0, bf, a0);
      a1 = MFMA16(af1, bf, a1);
    }
    if (pf) Xw[pb * 72 + pd] = (_Float16)xv;
    // P1 update (lane-local)
    H0w[b * 136 + j0] = (_Float16)cellup(a0, b0a, c0a);
    H0w[b * 136 + j1] = (_Float16)cellup(a1, b0b, c0b);
    __syncthreads();

    // ---- P2: gates1^T = [Wih1;Whh1]^T x [h0new; h1]  (K=256, 8 k-steps) ----
    a0 = (f32x4){0.f, 0.f, 0.f, 0.f};
    a1 = (f32x4){0.f, 0.f, 0.f, 0.f};
#pragma unroll
    for (int ks = 0; ks < 8; ++ks) {
      const _Float16* src = (ks < 4) ? (const _Float16*)H0w : H1r;
      h8 bf = ldfrag(src, b * 272 + (ks & 3) * 64 + khi * 16);
      h8 af0 = W2[ks * 2048 + aoff0];
      h8 af1 = W2[ks * 2048 + aoff1];
      a0 = MFMA16(af0, bf, a0);
      a1 = MFMA16(af1, bf, a1);
    }
    H1w[b * 136 + j0] = (_Float16)cellup(a0, b1a, c1a);
    H1w[b * 136 + j1] = (_Float16)cellup(a1, b1b, c1b);
    // no 2nd barrier needed: next P1 doesn't read H1; P2(t+1)'s H1 reads are
    // separated from these writes by barrier1(t+1). x/H0 hazards checked.
  }

  // final states (each lane wrote its own (b,j) h values; c in regs)
  const int r = row0 + b;
  st[0 * Bsz * Hsz + r * Hsz + j0] = (float)sH0[0][b * 136 + j0];
  st[0 * Bsz * Hsz + r * Hsz + j1] = (float)sH0[0][b * 136 + j1];
  st[1 * Bsz * Hsz + r * Hsz + j0] = c0a;
  st[1 * Bsz * Hsz + r * Hsz + j1] = c0b;
  st[2 * Bsz * Hsz + r * Hsz + j0] = (float)sH1[0][b * 136 + j0];
  st[2 * Bsz * Hsz + r * Hsz + j1] = (float)sH1[0][b * 136 + j1];
  st[3 * Bsz * Hsz + r * Hsz + j0] = c1a;
  st[3 * Bsz * Hsz + r * Hsz + j1] = c1b;
}

// ================= decoder =================
__global__ void __launch_bounds__(1024)
dec_kernel(const h8* __restrict__ W1 /*K=256: [Whh0;W']*/,
           const h8* __restrict__ W2 /*K=256: [Wih1;Whh1]*/,
           const float* __restrict__ b00p, const float* __restrict__ b0tp,
           const float* __restrict__ b1p, const float* __restrict__ st,
           _Float16* __restrict__ h1g) {
  __shared__ _Float16 sH0[2][16 * 136];
  __shared__ _Float16 sH1[2][16 * 136];

  const int tid = threadIdx.x;
  const int w = tid >> 6, lane = tid & 63;
  const int khi = lane >> 4, b = lane & 15;
  const int row0 = blockIdx.x << 4;
  const int aoff0 = (32 * w + b) * 4 + khi;
  const int aoff1 = aoff0 + 64;
  const int j0 = 8 * w + khi, j1 = j0 + 4;

  // init from encoder state
  for (int q = 0; q < 2; ++q) {
    int i = tid + q * 1024;                // 2048 = 16 rows x 128 j
    int rr = i >> 7, jj = i & 127;
    sH0[0][rr * 136 + jj] = (_Float16)st[0 * Bsz * Hsz + (row0 + rr) * Hsz + jj];
    sH1[0][rr * 136 + jj] = (_Float16)st[2 * Bsz * Hsz + (row0 + rr) * Hsz + jj];
  }
  float c0a = st[1 * Bsz * Hsz + (row0 + b) * Hsz + j0];
  float c0b = st[1 * Bsz * Hsz + (row0 + b) * Hsz + j1];
  float c1a = st[3 * Bsz * Hsz + (row0 + b) * Hsz + j0];
  float c1b = st[3 * Bsz * Hsz + (row0 + b) * Hsz + j1];

  const int nb0 = 32 * w + 4 * khi;
  const f32x4 b00a = *(const f32x4*)&b00p[nb0];
  const f32x4 b00b = *(const f32x4*)&b00p[nb0 + 16];
  const f32x4 b0ta = *(const f32x4*)&b0tp[nb0];
  const f32x4 b0tb = *(const f32x4*)&b0tp[nb0 + 16];
  const f32x4 b1a = *(const f32x4*)&b1p[nb0];
  const f32x4 b1b = *(const f32x4*)&b1p[nb0 + 16];
  __syncthreads();

  for (int t = 0; t < Ssz; ++t) {
    const int cur = t & 1;
    const _Float16* H0r = sH0[cur];
    _Float16* H0w = sH0[cur ^ 1];
    const _Float16* H1r = sH1[cur];
    _Float16* H1w = sH1[cur ^ 1];

    // ---- P1: gates0^T = [Whh0;W']^T x [h0; h1prev]; t=0: y=0 -> Whh0 half only
    f32x4 a0 = {0.f, 0.f, 0.f, 0.f}, a1 = {0.f, 0.f, 0.f, 0.f};
    if (t > 0) {
#pragma unroll
      for (int ks = 0; ks < 8; ++ks) {
        const _Float16* src = (ks < 4) ? H0r : H1r;
        h8 bf = ldfrag(src, b * 272 + (ks & 3) * 64 + khi * 16);
        h8 af0 = W1[ks * 2048 + aoff0];
        h8 af1 = W1[ks * 2048 + aoff1];
        a0 = MFMA16(af0, bf, a0);
        a1 = MFMA16(af1, bf, a1);
      }
    } else {
#pragma unroll
      for (int ks = 0; ks < 4; ++ks) {
        h8 bf = ldfrag(H0r, b * 272 + ks * 64 + khi * 16);
        h8 af0 = W1[ks * 2048 + aoff0];
        h8 af1 = W1[ks * 2048 + aoff1];
        a0 = MFMA16(af0, bf, a0);
        a1 = MFMA16(af1, bf, a1);
      }
    }
    H0w[b * 136 + j0] = (_Float16)cellup(a0, t ? b0ta : b00a, c0a);
    H0w[b * 136 + j1] = (_Float16)cellup(a1, t ? b0tb : b00b, c0b);
    __syncthreads();

    // ---- P2: gates1^T = [Wih1;Whh1]^T x [h0new; h1prev] ----
    a0 = (f32x4){0.f, 0.f, 0.f, 0.f};
    a1 = (f32x4){0.f, 0.f, 0.f, 0.f};
#pragma unroll
    for (int ks = 0; ks < 8; ++ks) {
      const _Float16* src = (ks < 4) ? (const _Float16*)H0w : H1r;
      h8 bf = ldfrag(src, b * 272 + (ks & 3) * 64 + khi * 16);
      h8 af0 = W2[ks * 2048 + aoff0];
      h8 af1 = W2[ks * 2048 + aoff1];
      a0 = MFMA16(af0, bf, a0);
      a1 = MFMA16(af1, bf, a1);
    }
    {
      float h0v = cellup(a0, b1a, c1a);
      float h1v = cellup(a1, b1b, c1b);
      H1w[b * 136 + j0] = (_Float16)h0v;
      H1w[b * 136 + j1] = (_Float16)h1v;
      size_t ob = ((size_t)(row0 + b) * Ssz + t) * Hsz;
      h1g[ob + j0] = (_Float16)h0v;      // epilogue fc input (in-place d_out)
      h1g[ob + j1] = (_Float16)h1v;
    }
    __syncthreads();                      // next P1 reads H1w
  }
}

// Epilogue: out[rowt][j] = fcb[j] + h1[rowt].fcW[j]; in-place over d_out.
__global__ void __launch_bounds__(256)
out_kernel(const float* __restrict__ fcw, const float* __restrict__ fcb,
           float* __restrict__ out) {
  __shared__ h8 s_fc[64][17];
  __shared__ h8 s_h[64][16];
  const int tid = threadIdx.x;
  const size_t base = (size_t)blockIdx.x * 64;
  const h8* h1g = (const h8*)out;
#pragma unroll
  for (int i = 0; i < 4; ++i) {
    int idx = tid + 256 * i;
    s_h[idx >> 4][idx & 15] = h1g[base * 16 + idx];
  }
#pragma unroll
  for (int i = 0; i < 4; ++i) {
    int idx = tid + 256 * i;
    int jj = idx >> 4, k8 = idx & 15;
    h8 v;
#pragma unroll
    for (int e = 0; e < 8; ++e) v[e] = (_Float16)fcw[jj * 128 + k8 * 8 + e];
    s_fc[jj][k8] = v;
  }
  __syncthreads();
  const int j = tid & 63, rg = tid >> 6;
  const float bj = fcb[j];
#pragma unroll
  for (int i = 0; i < 16; ++i) {
    int rr = rg * 16 + i;
    float a0 = 0.f, a1 = 0.f;
#pragma unroll
    for (int k = 0; k < 16; k += 2) {
      a0 = dot8(s_h[rr][k], s_fc[j][k], a0);
      a1 = dot8(s_h[rr][k + 1], s_fc[j][k + 1], a1);
    }
    out[(base + rr) * 64 + j] = bj + a0 + a1;
  }
}

// ---- prep kernels ----

// Wp32[c][h] = sum_d Wih0_dec[c][d] * fcW[d][h]  (original gate-row index c)
__global__ void wprime32_kernel(const float* __restrict__ wih0d,
                                const float* __restrict__ fcw,
                                float* __restrict__ o) {
  int idx = blockIdx.x * 256 + threadIdx.x;
  if (idx >= 512 * 128) return;
  int c = idx >> 7, h = idx & 127;
  float s = 0.f;
  for (int d = 0; d < 64; ++d) s += wih0d[c * 64 + d] * fcw[d * 128 + h];
  o[idx] = s;
}

// frag-linear pack: dst[((ks*512+n)*4+khi)] h8, elem e = W[permcol(n)][k],
// k = ks*32+khi*8+e, from stacked [s0 (K0) ; s1 (K1)]
__global__ void packfrag_kernel(h8* __restrict__ o, const float* __restrict__ s0,
                                int K0, const float* __restrict__ s1, int K1) {
  int tot = ((K0 + K1) >> 5) * 2048;
  int idx = blockIdx.x * 256 + threadIdx.x;
  if (idx >= tot) return;
  int khi = idx & 3;
  int n = (idx >> 2) & 511;
  int ks = idx >> 11;
  int c = permcol(n);
  h8 v;
#pragma unroll
  for (int e = 0; e < 8; ++e) {
    int k = ks * 32 + khi * 8 + e;
    float val = (k < K0) ? s0[c * K0 + k] : s1[c * K1 + (k - K0)];
    v[e] = (_Float16)val;
  }
  o[idx] = v;
}

// bias in packed-n order
__global__ void biaspk_kernel(const float* __restrict__ a, const float* __restrict__ b,
                              float* __restrict__ o) {
  int n = blockIdx.x * 256 + threadIdx.x;
  if (n >= 512) return;
  int c = permcol(n);
  o[n] = a[c] + b[c];
}

// + fcb @ Wih0_dec^T term folded in (for t>0 feedback)
__global__ void biaspk_fcb_kernel(const float* __restrict__ a, const float* __restrict__ b,
                                  const float* __restrict__ wih0d,
                                  const float* __restrict__ fcb,
                                  float* __restrict__ o) {
  int n = blockIdx.x * 256 + threadIdx.x;
  if (n >= 512) return;
  int c = permcol(n);
  float s = a[c] + b[c];
  for (int d = 0; d < 64; ++d) s += fcb[d] * wih0d[c * 64 + d];
  o[n] = s;
}

extern "C" void kernel_launch(void* const* d_in, const int* in_sizes, int n_in,
                              void* d_out, int out_size, void* d_ws, size_t ws_size,
                              hipStream_t stream) {
  (void)in_sizes; (void)n_in; (void)out_size; (void)ws_size;
  char* ws = (char*)d_ws;
  size_t off = 0;
  auto take = [&](size_t bytes) {
    char* p = ws + off;
    off += (bytes + 255) & ~(size_t)255;
    return p;
  };

  h8* e_w1 = (h8*)take(6 * 2048 * 16);     // enc P1 K=192
  h8* e_w2 = (h8*)take(8 * 2048 * 16);     // enc P2 K=256
  h8* d_w1 = (h8*)take(8 * 2048 * 16);     // dec P1 K=256 [Whh0;W']
  h8* d_w2 = (h8*)take(8 * 2048 * 16);     // dec P2 K=256
  float* wp32  = (float*)take(512 * 128 * 4);
  float* b_e0  = (float*)take(512 * 4);
  float* b_e1  = (float*)take(512 * 4);
  float* b_d00 = (float*)take(512 * 4);
  float* b_d0t = (float*)take(512 * 4);
  float* b_d1  = (float*)take(512 * 4);
  float* st    = (float*)take(4 * Bsz * Hsz * 4);

  const float* x = (const float*)d_in[0];

  wprime32_kernel<<<256, 256, 0, stream>>>((const float*)d_in[9], (const float*)d_in[17], wp32);

  packfrag_kernel<<<48, 256, 0, stream>>>(e_w1, (const float*)d_in[1], 64,
                                          (const float*)d_in[2], 128);
  packfrag_kernel<<<64, 256, 0, stream>>>(e_w2, (const float*)d_in[5], 128,
                                          (const float*)d_in[6], 128);
  packfrag_kernel<<<64, 256, 0, stream>>>(d_w1, (const float*)d_in[10], 128,
                                          wp32, 128);
  packfrag_kernel<<<64, 256, 0, stream>>>(d_w2, (const float*)d_in[13], 128,
                                          (const float*)d_in[14], 128);

  biaspk_kernel<<<2, 256, 0, stream>>>((const float*)d_in[3], (const float*)d_in[4], b_e0);
  biaspk_kernel<<<2, 256, 0, stream>>>((const float*)d_in[7], (const float*)d_in[8], b_e1);
  biaspk_kernel<<<2, 256, 0, stream>>>((const float*)d_in[11], (const float*)d_in[12], b_d00);
  biaspk_kernel<<<2, 256, 0, stream>>>((const float*)d_in[15], (const float*)d_in[16], b_d1);
  biaspk_fcb_kernel<<<2, 256, 0, stream>>>((const float*)d_in[11], (const float*)d_in[12],
                                           (const float*)d_in[9], (const float*)d_in[18], b_d0t);

  enc_kernel<<<16, 1024, 0, stream>>>(x, e_w1, e_w2, b_e0, b_e1, st);
  dec_kernel<<<16, 1024, 0, stream>>>(d_w1, d_w2, b_d00, b_d0t, b_d1, st,
                                      (_Float16*)d_out);
  out_kernel<<<(Bsz * Ssz) / 64, 256, 0, stream>>>((const float*)d_in[17],
                                                   (const float*)d_in[18], (float*)d_out);
}

// Round 8
// 4275.375 us; speedup vs baseline: 1.5267x; 1.5267x over previous
//
#include <hip/hip_runtime.h>
#include <hip/hip_fp16.h>

// LSTM autoencoder B=256,S=512,D=64,H=128 — weight-partitioned MFMA.
// 16 groups x 16 batch rows; each group = 4 WGs (256 thr) on 4 CUs.
// WG q holds gate-quarter q's weights ENTIRELY IN LDS (dec 128KB, enc 112KB).
// Per step: each WG computes its 128 gates (MFMA 16x16x32 f16, R7-validated
// fragment maps), lane-local cell update for its 32-j h-slice, then the 4 WGs
// exchange 1KB h-slices via sentinel-coded LLC mailboxes (agent-scope atomics,
// payload-is-token, no fences). Zero steady-state weight traffic.
// fc projection: epilogue kernel, in-place in d_out (R7-validated).

typedef _Float16 h2 __attribute__((ext_vector_type(2)));
typedef _Float16 h8 __attribute__((ext_vector_type(8)));
typedef float f32x4 __attribute__((ext_vector_type(4)));

#define Bsz 256
#define Ssz 512
#define Hsz 128
#define NG 16            // groups
#define SENT 0xFFFFFFFFu

#define MFMA16(A, B, C) __builtin_amdgcn_mfma_f32_16x16x32_f16(A, B, C, 0, 0, 0)
// mailbox dword index: [group][phase][slot][producer][consumer] x 256 dwords
#define MB(g, ph, slot, prod, cons) \
  ((((((g) * 2 + (ph)) * 4 + (slot)) * 4 + (prod)) * 4 + (cons)) * 256)
#define MB_DWORDS (NG * 2 * 4 * 4 * 4 * 256)

__device__ __forceinline__ float fdot2f(h2 a, h2 b, float c) {
#if __has_builtin(__builtin_amdgcn_fdot2)
  return __builtin_amdgcn_fdot2(a, b, c, false);
#else
  return c + (float)a[0] * (float)b[0] + (float)a[1] * (float)b[1];
#endif
}

__device__ __forceinline__ float dot8(h8 v, h8 w, float acc) {
  h2 v0 = __builtin_shufflevector(v, v, 0, 1);
  h2 v1 = __builtin_shufflevector(v, v, 2, 3);
  h2 v2 = __builtin_shufflevector(v, v, 4, 5);
  h2 v3 = __builtin_shufflevector(v, v, 6, 7);
  h2 w0 = __builtin_shufflevector(w, w, 0, 1);
  h2 w1 = __builtin_shufflevector(w, w, 2, 3);
  h2 w2 = __builtin_shufflevector(w, w, 4, 5);
  h2 w3 = __builtin_shufflevector(w, w, 6, 7);
  acc = fdot2f(v0, w0, acc);
  acc = fdot2f(v1, w1, acc);
  acc = fdot2f(v2, w2, acc);
  acc = fdot2f(v3, w3, acc);
  return acc;
}

__device__ __forceinline__ float sigm(float v) { return 1.f / (1.f + __expf(-v)); }
__device__ __forceinline__ float tanh_f(float v) { return 2.f / (1.f + __expf(-2.f * v)) - 1.f; }

__device__ __forceinline__ int permcol(int n) { return (n & 3) * 128 + (n >> 2); }

__device__ __forceinline__ h8 ldfrag(const _Float16* p, int byteoff) {
  return *(const h8*)((const char*)p + byteoff);
}

// lane-local LSTM cell update: a = accum (i,f,g,o), bb = bias; returns h
__device__ __forceinline__ float cellup(f32x4 a, f32x4 bb, float& c) {
  float ig = sigm(a[0] + bb[0]);
  float fg = sigm(a[1] + bb[1]);
  float gg = tanh_f(a[2] + bb[2]);
  float og = sigm(a[3] + bb[3]);
  c = fg * c + ig * gg;
  return og * tanh_f(c);
}

// h-slice exchange: own slice already in sH (barrier'd); publishes to 3 peers'
// mailboxes, polls own 3 inboxes (payload-is-token), resets to sentinel.
// Caller must __syncthreads() before and after.
__device__ __forceinline__ void exch(unsigned* mbox, _Float16* sH, int g, int ph,
                                     int slot, int q, int tid) {
  const int b = tid >> 4, jp = tid & 15;
  unsigned v = *(const unsigned*)((const char*)sH + b * 272 + 64 * q + 4 * jp);
  asm volatile("s_waitcnt vmcnt(0)" ::: "memory");  // prior resets complete
#pragma unroll
  for (int p = 0; p < 4; ++p)
    if (p != q)
      __hip_atomic_store(&mbox[MB(g, ph, slot, q, p) + tid], v,
                         __ATOMIC_RELAXED, __HIP_MEMORY_SCOPE_AGENT);
#pragma unroll
  for (int p = 0; p < 4; ++p)
    if (p != q) {
      unsigned* s = &mbox[MB(g, ph, slot, p, q) + tid];
      unsigned u;
      int it = 0;
      do {
        u = __hip_atomic_load(s, __ATOMIC_RELAXED, __HIP_MEMORY_SCOPE_AGENT);
      } while (u == SENT && ++it < (1 << 18));
      *(unsigned*)((char*)sH + b * 272 + 64 * p + 4 * jp) = u;
      __hip_atomic_store(s, SENT, __ATOMIC_RELAXED, __HIP_MEMORY_SCOPE_AGENT);
    }
}

// ================= encoder =================
__global__ void __launch_bounds__(256)
enc_kernel(const float* __restrict__ x,
           const h8* __restrict__ w1g /*K=192 [Wih0;Whh0] frag-linear*/,
           const h8* __restrict__ w2g /*K=256 [Wih1;Whh1]*/,
           const float* __restrict__ b0p, const float* __restrict__ b1p,
           float* __restrict__ st, unsigned* __restrict__ mbox) {
  __shared__ h8 sW1[6 * 512];             // 48 KiB quarter of [Wih0;Whh0]
  __shared__ h8 sW2[8 * 512];             // 64 KiB quarter of [Wih1;Whh1]
  __shared__ _Float16 sH0[2][16 * 136];   // full h0, 272B row stride
  __shared__ _Float16 sH1[2][16 * 136];
  __shared__ _Float16 sX[2][16 * 72];     // x_t, 144B row stride

  const int tid = threadIdx.x;
  const int g = blockIdx.x & 15, q = blockIdx.x >> 4;
  const int row0 = g << 4;
  const int w = tid >> 6, lane = tid & 63;
  const int khi = lane >> 4, b = lane & 15;
  const int aoffA = ((32 * w + b) << 2) + khi;  // h8 idx within a ks-block
  const int aoffB = aoffA + 64;
  const int j0 = 32 * q + 8 * w + khi, j1 = j0 + 4;

  for (int i = tid; i < 6 * 512; i += 256)
    sW1[i] = w1g[(i >> 9) * 2048 + 512 * q + (i & 511)];
  for (int i = tid; i < 8 * 512; i += 256)
    sW2[i] = w2g[(i >> 9) * 2048 + 512 * q + (i & 511)];
  for (int i = tid; i < 16 * 136; i += 256) {
    sH0[0][i] = (_Float16)0.f;
    sH1[0][i] = (_Float16)0.f;
  }
#pragma unroll
  for (int kk = 0; kk < 4; ++kk) {  // preload x(0)
    int e = tid + 256 * kk, bb = e >> 6, dd = e & 63;
    sX[0][bb * 72 + dd] = (_Float16)x[((size_t)(row0 + bb) * Ssz + 0) * 64 + dd];
  }
  const f32x4 b0a = *(const f32x4*)&b0p[4 * j0];
  const f32x4 b0b = *(const f32x4*)&b0p[4 * j0 + 16];
  const f32x4 b1a = *(const f32x4*)&b1p[4 * j0];
  const f32x4 b1b = *(const f32x4*)&b1p[4 * j0 + 16];
  float c0a = 0.f, c0b = 0.f, c1a = 0.f, c1b = 0.f;
  float h0a = 0.f, h0b = 0.f, h1a = 0.f, h1b = 0.f;
  __syncthreads();

  for (int t = 0; t < Ssz; ++t) {
    const int cur = t & 1, nxt = cur ^ 1;
    // prefetch x(t+1)
    float xv[4];
    const bool pf = (t + 1 < Ssz);
    if (pf) {
#pragma unroll
      for (int kk = 0; kk < 4; ++kk) {
        int e = tid + 256 * kk;
        xv[kk] = x[((size_t)(row0 + (e >> 6)) * Ssz + (t + 1)) * 64 + (e & 63)];
      }
    }
    // ---- P1: gates0 quarter = [Wih0;Whh0]^T x [x_t; h0(t-1)], K=192 ----
    f32x4 a0 = {0.f, 0.f, 0.f, 0.f}, a1 = {0.f, 0.f, 0.f, 0.f};
#pragma unroll
    for (int ks = 0; ks < 6; ++ks) {
      h8 bf = (ks < 2) ? ldfrag(sX[cur], b * 144 + ks * 64 + khi * 16)
                       : ldfrag(sH0[cur], b * 272 + (ks - 2) * 64 + khi * 16);
      a0 = MFMA16(sW1[ks * 512 + aoffA], bf, a0);
      a1 = MFMA16(sW1[ks * 512 + aoffB], bf, a1);
    }
    h0a = cellup(a0, b0a, c0a);
    h0b = cellup(a1, b0b, c0b);
    sH0[nxt][b * 136 + j0] = (_Float16)h0a;
    sH0[nxt][b * 136 + j1] = (_Float16)h0b;
    if (pf) {
#pragma unroll
      for (int kk = 0; kk < 4; ++kk) {
        int e = tid + 256 * kk;
        sX[nxt][(e >> 6) * 72 + (e & 63)] = (_Float16)xv[kk];
      }
    }
    __syncthreads();
    exch(mbox, sH0[nxt], g, 0, t & 3, q, tid);   // full h0(t) assembled
    __syncthreads();
    // ---- P2: gates1 quarter = [Wih1;Whh1]^T x [h0(t); h1(t-1)], K=256 ----
    a0 = (f32x4){0.f, 0.f, 0.f, 0.f};
    a1 = (f32x4){0.f, 0.f, 0.f, 0.f};
#pragma unroll
    for (int ks = 0; ks < 8; ++ks) {
      const _Float16* src = (ks < 4) ? sH0[nxt] : sH1[cur];
      h8 bf = ldfrag(src, b * 272 + (ks & 3) * 64 + khi * 16);
      a0 = MFMA16(sW2[ks * 512 + aoffA], bf, a0);
      a1 = MFMA16(sW2[ks * 512 + aoffB], bf, a1);
    }
    h1a = cellup(a0, b1a, c1a);
    h1b = cellup(a1, b1b, c1b);
    sH1[nxt][b * 136 + j0] = (_Float16)h1a;
    sH1[nxt][b * 136 + j1] = (_Float16)h1b;
    __syncthreads();
    if (pf) {
      exch(mbox, sH1[nxt], g, 1, t & 3, q, tid);  // full h1(t)
      __syncthreads();
    }
  }
  // final states (lane-local slices; all WGs cover disjoint j)
  const int r = row0 + b;
  st[0 * Bsz * Hsz + r * Hsz + j0] = h0a;
  st[0 * Bsz * Hsz + r * Hsz + j1] = h0b;
  st[1 * Bsz * Hsz + r * Hsz + j0] = c0a;
  st[1 * Bsz * Hsz + r * Hsz + j1] = c0b;
  st[2 * Bsz * Hsz + r * Hsz + j0] = h1a;
  st[2 * Bsz * Hsz + r * Hsz + j1] = h1b;
  st[3 * Bsz * Hsz + r * Hsz + j0] = c1a;
  st[3 * Bsz * Hsz + r * Hsz + j1] = c1b;
}

// ================= decoder =================
__global__ void __launch_bounds__(256)
dec_kernel(const h8* __restrict__ w1g /*K=256 [Whh0;W']*/,
           const h8* __restrict__ w2g /*K=256 [Wih1;Whh1]*/,
           const float* __restrict__ b00p, const float* __restrict__ b0tp,
           const float* __restrict__ b1p, const float* __restrict__ st,
           _Float16* __restrict__ h1g, unsigned* __restrict__ mbox) {
  __shared__ h8 sW1[8 * 512];             // 64 KiB quarter of [Whh0;W']
  __shared__ h8 sW2[8 * 512];             // 64 KiB quarter of [Wih1;Whh1]
  __shared__ _Float16 sH0[2][16 * 136];
  __shared__ _Float16 sH1[2][16 * 136];

  const int tid = threadIdx.x;
  const int g = blockIdx.x & 15, q = blockIdx.x >> 4;
  const int row0 = g << 4;
  const int w = tid >> 6, lane = tid & 63;
  const int khi = lane >> 4, b = lane & 15;
  const int aoffA = ((32 * w + b) << 2) + khi;
  const int aoffB = aoffA + 64;
  const int j0 = 32 * q + 8 * w + khi, j1 = j0 + 4;

  for (int i = tid; i < 8 * 512; i += 256) {
    sW1[i] = w1g[(i >> 9) * 2048 + 512 * q + (i & 511)];
    sW2[i] = w2g[(i >> 9) * 2048 + 512 * q + (i & 511)];
  }
  for (int kk = 0; kk < 8; ++kk) {  // full h from encoder state
    int e = tid + 256 * kk, rr = e >> 7, jj = e & 127;
    sH0[0][rr * 136 + jj] = (_Float16)st[0 * Bsz * Hsz + (row0 + rr) * Hsz + jj];
    sH1[0][rr * 136 + jj] = (_Float16)st[2 * Bsz * Hsz + (row0 + rr) * Hsz + jj];
  }
  float c0a = st[1 * Bsz * Hsz + (row0 + b) * Hsz + j0];
  float c0b = st[1 * Bsz * Hsz + (row0 + b) * Hsz + j1];
  float c1a = st[3 * Bsz * Hsz + (row0 + b) * Hsz + j0];
  float c1b = st[3 * Bsz * Hsz + (row0 + b) * Hsz + j1];
  const f32x4 b00a = *(const f32x4*)&b00p[4 * j0];
  const f32x4 b00b = *(const f32x4*)&b00p[4 * j0 + 16];
  const f32x4 b0ta = *(const f32x4*)&b0tp[4 * j0];
  const f32x4 b0tb = *(const f32x4*)&b0tp[4 * j0 + 16];
  const f32x4 b1a = *(const f32x4*)&b1p[4 * j0];
  const f32x4 b1b = *(const f32x4*)&b1p[4 * j0 + 16];
  __syncthreads();

  for (int t = 0; t < Ssz; ++t) {
    const int cur = t & 1, nxt = cur ^ 1;
    // ---- P1: [Whh0;W']^T x [h0(t-1); h1(t-1)]; t=0: y=0 -> Whh0 half only
    f32x4 a0 = {0.f, 0.f, 0.f, 0.f}, a1 = {0.f, 0.f, 0.f, 0.f};
    const int nks = (t > 0) ? 8 : 4;
    for (int ks = 0; ks < nks; ++ks) {
      const _Float16* src = (ks < 4) ? sH0[cur] : sH1[cur];
      h8 bf = ldfrag(src, b * 272 + (ks & 3) * 64 + khi * 16);
      a0 = MFMA16(sW1[ks * 512 + aoffA], bf, a0);
      a1 = MFMA16(sW1[ks * 512 + aoffB], bf, a1);
    }
    float h0a = cellup(a0, t ? b0ta : b00a, c0a);
    float h0b = cellup(a1, t ? b0tb : b00b, c0b);
    sH0[nxt][b * 136 + j0] = (_Float16)h0a;
    sH0[nxt][b * 136 + j1] = (_Float16)h0b;
    __syncthreads();
    exch(mbox, sH0[nxt], g, 0, t & 3, q, tid);
    __syncthreads();
    // ---- P2: [Wih1;Whh1]^T x [h0(t); h1(t-1)] ----
    a0 = (f32x4){0.f, 0.f, 0.f, 0.f};
    a1 = (f32x4){0.f, 0.f, 0.f, 0.f};
#pragma unroll
    for (int ks = 0; ks < 8; ++ks) {
      const _Float16* src = (ks < 4) ? sH0[nxt] : sH1[cur];
      h8 bf = ldfrag(src, b * 272 + (ks & 3) * 64 + khi * 16);
      a0 = MFMA16(sW2[ks * 512 + aoffA], bf, a0);
      a1 = MFMA16(sW2[ks * 512 + aoffB], bf, a1);
    }
    float h1a = cellup(a0, b1a, c1a);
    float h1b = cellup(a1, b1b, c1b);
    sH1[nxt][b * 136 + j0] = (_Float16)h1a;
    sH1[nxt][b * 136 + j1] = (_Float16)h1b;
    {
      size_t ob = ((size_t)(row0 + b) * Ssz + t) * Hsz;
      h1g[ob + j0] = (_Float16)h1a;   // epilogue fc input (in-place d_out)
      h1g[ob + j1] = (_Float16)h1b;
    }
    __syncthreads();
    if (t + 1 < Ssz) {
      exch(mbox, sH1[nxt], g, 1, t & 3, q, tid);
      __syncthreads();
    }
  }
}

// Epilogue: out[rowt][j] = fcb[j] + h1[rowt].fcW[j]; in-place over d_out.
__global__ void __launch_bounds__(256)
out_kernel(const float* __restrict__ fcw, const float* __restrict__ fcb,
           float* __restrict__ out) {
  __shared__ h8 s_fc[64][17];
  __shared__ h8 s_h[64][16];
  const int tid = threadIdx.x;
  const size_t base = (size_t)blockIdx.x * 64;
  const h8* h1g = (const h8*)out;
#pragma unroll
  for (int i = 0; i < 4; ++i) {
    int idx = tid + 256 * i;
    s_h[idx >> 4][idx & 15] = h1g[base * 16 + idx];
  }
#pragma unroll
  for (int i = 0; i < 4; ++i) {
    int idx = tid + 256 * i;
    int jj = idx >> 4, k8 = idx & 15;
    h8 v;
#pragma unroll
    for (int e = 0; e < 8; ++e) v[e] = (_Float16)fcw[jj * 128 + k8 * 8 + e];
    s_fc[jj][k8] = v;
  }
  __syncthreads();
  const int j = tid & 63, rg = tid >> 6;
  const float bj = fcb[j];
#pragma unroll
  for (int i = 0; i < 16; ++i) {
    int rr = rg * 16 + i;
    float a0 = 0.f, a1 = 0.f;
#pragma unroll
    for (int k = 0; k < 16; k += 2) {
      a0 = dot8(s_h[rr][k], s_fc[j][k], a0);
      a1 = dot8(s_h[rr][k + 1], s_fc[j][k + 1], a1);
    }
    out[(base + rr) * 64 + j] = bj + a0 + a1;
  }
}

// ---- prep kernels (R7-validated) ----

__global__ void wprime32_kernel(const float* __restrict__ wih0d,
                                const float* __restrict__ fcw,
                                float* __restrict__ o) {
  int idx = blockIdx.x * 256 + threadIdx.x;
  if (idx >= 512 * 128) return;
  int c = idx >> 7, h = idx & 127;
  float s = 0.f;
  for (int d = 0; d < 64; ++d) s += wih0d[c * 64 + d] * fcw[d * 128 + h];
  o[idx] = s;
}

// frag-linear pack: o[(ks*512+n)*4+khi] h8, elem e = Wstack[permcol(n)][k],
// k = ks*32+khi*8+e, stacked [s0 (K0); s1 (K1)]
__global__ void packfrag_kernel(h8* __restrict__ o, const float* __restrict__ s0,
                                int K0, const float* __restrict__ s1, int K1) {
  int tot = ((K0 + K1) >> 5) * 2048;
  int idx = blockIdx.x * 256 + threadIdx.x;
  if (idx >= tot) return;
  int khi = idx & 3;
  int n = (idx >> 2) & 511;
  int ks = idx >> 11;
  int c = permcol(n);
  h8 v;
#pragma unroll
  for (int e = 0; e < 8; ++e) {
    int k = ks * 32 + khi * 8 + e;
    float val = (k < K0) ? s0[c * K0 + k] : s1[c * K1 + (k - K0)];
    v[e] = (_Float16)val;
  }
  o[idx] = v;
}

__global__ void biaspk_kernel(const float* __restrict__ a, const float* __restrict__ b,
                              float* __restrict__ o) {
  int n = blockIdx.x * 256 + threadIdx.x;
  if (n >= 512) return;
  int c = permcol(n);
  o[n] = a[c] + b[c];
}

__global__ void biaspk_fcb_kernel(const float* __restrict__ a, const float* __restrict__ b,
                                  const float* __restrict__ wih0d,
                                  const float* __restrict__ fcb,
                                  float* __restrict__ o) {
  int n = blockIdx.x * 256 + threadIdx.x;
  if (n >= 512) return;
  int c = permcol(n);
  float s = a[c] + b[c];
  for (int d = 0; d < 64; ++d) s += fcb[d] * wih0d[c * 64 + d];
  o[n] = s;
}

extern "C" void kernel_launch(void* const* d_in, const int* in_sizes, int n_in,
                              void* d_out, int out_size, void* d_ws, size_t ws_size,
                              hipStream_t stream) {
  (void)in_sizes; (void)n_in; (void)out_size; (void)ws_size;
  char* ws = (char*)d_ws;
  size_t off = 0;
  auto take = [&](size_t bytes) {
    char* p = ws + off;
    off += (bytes + 255) & ~(size_t)255;
    return p;
  };

  h8* e_w1 = (h8*)take(6 * 2048 * 16);     // enc P1 K=192 [Wih0;Whh0]
  h8* e_w2 = (h8*)take(8 * 2048 * 16);     // enc P2 K=256 [Wih1;Whh1]
  h8* d_w1 = (h8*)take(8 * 2048 * 16);     // dec P1 K=256 [Whh0;W']
  h8* d_w2 = (h8*)take(8 * 2048 * 16);     // dec P2 K=256 [Wih1;Whh1]
  float* wp32  = (float*)take(512 * 128 * 4);
  float* b_e0  = (float*)take(512 * 4);
  float* b_e1  = (float*)take(512 * 4);
  float* b_d00 = (float*)take(512 * 4);
  float* b_d0t = (float*)take(512 * 4);
  float* b_d1  = (float*)take(512 * 4);
  float* st    = (float*)take(4 * Bsz * Hsz * 4);
  unsigned* mbox = (unsigned*)take(MB_DWORDS * 4);   // 2 MiB mailboxes

  const float* x = (const float*)d_in[0];

  hipMemsetAsync(mbox, 0xFF, MB_DWORDS * 4, stream);  // all-sentinel

  wprime32_kernel<<<256, 256, 0, stream>>>((const float*)d_in[9], (const float*)d_in[17], wp32);

  packfrag_kernel<<<48, 256, 0, stream>>>(e_w1, (const float*)d_in[1], 64,
                                          (const float*)d_in[2], 128);
  packfrag_kernel<<<64, 256, 0, stream>>>(e_w2, (const float*)d_in[5], 128,
                                          (const float*)d_in[6], 128);
  packfrag_kernel<<<64, 256, 0, stream>>>(d_w1, (const float*)d_in[10], 128,
                                          wp32, 128);
  packfrag_kernel<<<64, 256, 0, stream>>>(d_w2, (const float*)d_in[13], 128,
                                          (const float*)d_in[14], 128);

  biaspk_kernel<<<2, 256, 0, stream>>>((const float*)d_in[3], (const float*)d_in[4], b_e0);
  biaspk_kernel<<<2, 256, 0, stream>>>((const float*)d_in[7], (const float*)d_in[8], b_e1);
  biaspk_kernel<<<2, 256, 0, stream>>>((const float*)d_in[11], (const float*)d_in[12], b_d00);
  biaspk_kernel<<<2, 256, 0, stream>>>((const float*)d_in[15], (const float*)d_in[16], b_d1);
  biaspk_fcb_kernel<<<2, 256, 0, stream>>>((const float*)d_in[11], (const float*)d_in[12],
                                           (const float*)d_in[9], (const float*)d_in[18], b_d0t);

  enc_kernel<<<64, 256, 0, stream>>>(x, e_w1, e_w2, b_e0, b_e1, st, mbox);
  dec_kernel<<<64, 256, 0, stream>>>(d_w1, d_w2, b_d00, b_d0t, b_d1, st,
                                     (_Float16*)d_out, mbox);
  out_kernel<<<(Bsz * Ssz) / 64, 256, 0, stream>>>((const float*)d_in[17],
                                                   (const float*)d_in[18], (float*)d_out);
}